// Round 6
// baseline (190.887 us; speedup 1.0000x reference)
//
#include <hip/hip_runtime.h>
#include <stdint.h>

#define THR  1.0f
#define BETA 0.95f
#define SX   4096.0f            // x scale (2^12) -> no fp16 denormal flush
#define SW   512.0f             // W scale (2^9)
#define SINV (1.0f / (4096.0f * 512.0f))
#define W1N  (128 * 784)

typedef __attribute__((ext_vector_type(8)))  _Float16 f16x8;
typedef __attribute__((ext_vector_type(16))) float    f32x16;
typedef __attribute__((ext_vector_type(4)))  float    fvec4;

__device__ __forceinline__ void gll16(const float* g, float* l){
  __builtin_amdgcn_global_load_lds((const __attribute__((address_space(1))) void*)g,
                                   (__attribute__((address_space(3))) void*)l, 16, 0, 0);
}

// 2-term RNE fp16 split of scaled W1, written in MFMA-fragment order:
// fragment (gks 0..48, nf 0..3, term 0..1) is 1KB: lane (kg*32+r) holds 8 fp16
// for col h=nf*32+r, k=gks*16+kg*8.. — a wave's B-load is 1KB fully contiguous.
__global__ void split_w1(const float* __restrict__ W1, _Float16* __restrict__ wB){
  int i = blockIdx.x * 256 + threadIdx.x;
  if (i < W1N) {
    int h = i / 784, k = i % 784;
    float v = W1[i] * SW;
    _Float16 hi = (_Float16)v;
    _Float16 lo = (_Float16)(v - (float)hi);
    int ks = k >> 4, kg = (k >> 3) & 1, j = k & 7, nf = h >> 5, r = h & 31;
    int base = ((ks * 4 + nf) * 2) * 512 + (kg * 32 + r) * 8 + j;
    wB[base]       = hi;   // term 0
    wB[base + 512] = lo;   // term 1
  }
}

// cur1[m][h] = sum_k x[m][k]*W1[h][k] (scaled; bias in lif).
// Block: 4 waves, tile 128m x 128n. A staged via global_load_lds into swizzled
// 128row x 32k f32 LDS slabs (16KB, double-buffered; 24 slabs + 16-k tail).
// LDS 40KB -> 4 blocks/CU; launch_bounds(256,4) -> 16 waves/CU.
// 3 fp16 MFMAs (hh+hl+lh) per nf per k-step.
__launch_bounds__(256, 4)
__global__ void gemm1(const float* __restrict__ x,
                      const _Float16* __restrict__ wB,
                      float* __restrict__ cur1,
                      long row0){
  __shared__ float lds[10240];            // 2x4096 slab dbuf + 2048 tail = 40KB
  const int lane = threadIdx.x & 63;
  const int w    = threadIdx.x >> 6;
  const long blk_row0 = row0 + (long)blockIdx.x * 128;
  const int r  = lane & 31;
  const int kg = lane >> 5;
  const int row_a = w * 32 + r;           // this lane's A row within tile
  const int xr  = (row_a & 7) << 4;       // main-slab XOR swizzle (bytes)
  const int xr3 = (row_a & 3) << 4;       // tail XOR swizzle
  const f16x8* wv = (const f16x8*)wB;

  // ---- stage tail (k=768..783, 8KB) into lds[8192..] : 2 instrs/wave ----
  #pragma unroll
  for (int i = 0; i < 2; ++i) {
    int j = (w * 2 + i) * 64 + lane;      // 0..511
    int rw = j >> 2, q = (j & 3) << 4;
    int kb = q ^ ((rw & 3) << 4);
    gll16(x + (blk_row0 + rw) * 784 + 768 + (kb >> 2),
          &lds[8192 + (w * 2 + i) * 256]);
  }

  // stage one 16KB slab (s = 32-k slab index 0..23) into buffer bb
  #define STAGE(bb, s) {                                                     \
    _Pragma("unroll") for (int i = 0; i < 4; ++i) {                          \
      int j = (w * 4 + i) * 64 + lane;    /* 0..1023 */                      \
      int rw = j >> 3, q = (j & 7) << 4;                                     \
      int kb = q ^ ((rw & 7) << 4);                                          \
      gll16(x + (blk_row0 + rw) * 784 + (s) * 32 + (kb >> 2),                \
            &lds[(bb) * 4096 + (w * 4 + i) * 256]); } }

  f32x16 acc[4] = {};

  STAGE(0, 0);
  __syncthreads();                        // drain: slab 0 + tail ready

  #pragma unroll 2
  for (int s = 0; s < 24; ++s) {
    const int bb = s & 1;
    if (s + 1 < 24) STAGE(bb ^ 1, s + 1); // async prefetch next slab
    #pragma unroll
    for (int ksl = 0; ksl < 2; ++ksl) {
      const int gks = s * 2 + ksl;        // global 16-k step 0..47
      // B fragments: 8 x 1KB contiguous wave-loads (L1/L2-hot)
      f16x8 b[8];
      #pragma unroll
      for (int nf = 0; nf < 4; ++nf)
        #pragma unroll
        for (int t = 0; t < 2; ++t)
          b[nf * 2 + t] = wv[((gks * 4 + nf) * 2 + t) * 64 + lane];
      // A fragment: 2 swizzled ds_read_b128 + fp16 split
      int kb0 = ksl * 64 + kg * 32;       // byte offset within 128B row
      fvec4 a0 = *(const fvec4*)&lds[bb * 4096 + row_a * 32 + (((kb0)      ^ xr) >> 2)];
      fvec4 a1 = *(const fvec4*)&lds[bb * 4096 + row_a * 32 + (((kb0 + 16) ^ xr) >> 2)];
      f16x8 ah, al;
      #pragma unroll
      for (int j = 0; j < 8; ++j) {
        float v = ((j < 4) ? a0[j] : a1[j - 4]) * SX;
        _Float16 hh = (_Float16)v;
        ah[j] = hh; al[j] = (_Float16)(v - (float)hh);
      }
      #pragma unroll
      for (int nf = 0; nf < 4; ++nf) {
        acc[nf] = __builtin_amdgcn_mfma_f32_32x32x16_f16(ah, b[nf * 2],     acc[nf], 0, 0, 0);
        acc[nf] = __builtin_amdgcn_mfma_f32_32x32x16_f16(ah, b[nf * 2 + 1], acc[nf], 0, 0, 0);
        acc[nf] = __builtin_amdgcn_mfma_f32_32x32x16_f16(al, b[nf * 2],     acc[nf], 0, 0, 0);
      }
    }
    __syncthreads();                      // next slab staged, old buf free
  }

  // ---- tail k-step (gks=48) from tail LDS region ----
  {
    f16x8 b[8];
    #pragma unroll
    for (int nf = 0; nf < 4; ++nf)
      #pragma unroll
      for (int t = 0; t < 2; ++t)
        b[nf * 2 + t] = wv[((48 * 4 + nf) * 2 + t) * 64 + lane];
    int kb0 = kg * 32;
    fvec4 a0 = *(const fvec4*)&lds[8192 + row_a * 16 + (((kb0)      ^ xr3) >> 2)];
    fvec4 a1 = *(const fvec4*)&lds[8192 + row_a * 16 + (((kb0 + 16) ^ xr3) >> 2)];
    f16x8 ah, al;
    #pragma unroll
    for (int j = 0; j < 8; ++j) {
      float v = ((j < 4) ? a0[j] : a1[j - 4]) * SX;
      _Float16 hh = (_Float16)v;
      ah[j] = hh; al[j] = (_Float16)(v - (float)hh);
    }
    #pragma unroll
    for (int nf = 0; nf < 4; ++nf) {
      acc[nf] = __builtin_amdgcn_mfma_f32_32x32x16_f16(ah, b[nf * 2],     acc[nf], 0, 0, 0);
      acc[nf] = __builtin_amdgcn_mfma_f32_32x32x16_f16(ah, b[nf * 2 + 1], acc[nf], 0, 0, 0);
      acc[nf] = __builtin_amdgcn_mfma_f32_32x32x16_f16(al, b[nf * 2],     acc[nf], 0, 0, 0);
    }
  }

  // C/D layout (m74/m101-verified): col = lane&31, row = (reg&3)+8*(reg>>2)+4*(lane>>5)
  long m0 = (long)blockIdx.x * 128 + w * 32;
  #pragma unroll
  for (int nf = 0; nf < 4; ++nf)
    #pragma unroll
    for (int reg = 0; reg < 16; ++reg) {
      int rr = (reg & 3) + 8 * (reg >> 2) + 4 * kg;
      cur1[(m0 + rr) * 128 + nf * 32 + r] = acc[nf][reg] * SINV;
    }
  #undef STAGE
}

// LIF recurrence + layer 2. One wave per batch element b; lane owns h=lane, h=lane+64.
// Layer-2 reduction via ballot bitmask + per-lane bfe/cvt/fma over a 32-h chunk.
__launch_bounds__(256)
__global__ void lif(const float* __restrict__ cur1,
                    const float* __restrict__ b1,
                    const float* __restrict__ W2,
                    const float* __restrict__ b2,
                    float* __restrict__ out,
                    float* __restrict__ state1,
                    float* __restrict__ state2,
                    int t0, int tn){
  const int lane = threadIdx.x & 63;
  const int b = blockIdx.x * 4 + (threadIdx.x >> 6);
  const int o = lane & 15;
  const int c = lane >> 4;

  float wv[32];
  #pragma unroll
  for (int j = 0; j < 32; ++j) wv[j] = 0.f;
  if (o < 10) {
    #pragma unroll
    for (int j = 0; j < 32; ++j) wv[j] = W2[o * 128 + c * 32 + j];
  }
  float b1a = b1[lane], b1b = b1[64 + lane];
  float b2v = (lane < 10) ? b2[lane] : 0.f;

  float mem1a, mem1b, mem2;
  if (t0 == 0) { mem1a = 0.f; mem1b = 0.f; mem2 = 0.f; }
  else {
    mem1a = state1[b * 128 + lane];
    mem1b = state1[b * 128 + 64 + lane];
    mem2  = (lane < 10) ? state2[b * 10 + lane] : 0.f;
  }

  for (int t = t0; t < tn; ++t) {
    long base = ((long)(t - t0) * 4096 + b) * 128;
    float c1a = cur1[base + lane] + b1a;
    float c1b = cur1[base + 64 + lane] + b1b;
    float r1a = (mem1a > THR) ? THR : 0.f;
    float r1b = (mem1b > THR) ? THR : 0.f;
    mem1a = BETA * mem1a + c1a - r1a;
    mem1b = BETA * mem1b + c1b - r1b;

    uint64_t mA = __ballot(mem1a > THR);
    uint64_t mB = __ballot(mem1b > THR);
    uint64_t m64 = (c & 2) ? mB : mA;
    uint32_t bits = (uint32_t)(m64 >> ((c & 1) << 5));

    float s = 0.f;
    #pragma unroll
    for (int j = 0; j < 32; ++j)
      s = fmaf((float)((bits >> j) & 1u), wv[j], s);   // bfe+cvt+fma
    s += __shfl_xor(s, 16);
    s += __shfl_xor(s, 32);

    if (lane < 10) {
      float cur2 = s + b2v;
      float r2 = (mem2 > THR) ? THR : 0.f;
      mem2 = BETA * mem2 + cur2 - r2;
      float s2 = (mem2 > THR) ? 1.f : 0.f;
      long ob = (long)t * 40960 + (long)b * 10 + lane;
      out[ob] = s2;
      out[1228800 + ob] = mem2;
    }
  }

  if (tn < 30) {
    state1[b * 128 + lane] = mem1a;
    state1[b * 128 + 64 + lane] = mem1b;
    if (lane < 10) state2[b * 10 + lane] = mem2;
  }
}

extern "C" void kernel_launch(void* const* d_in, const int* in_sizes, int n_in,
                              void* d_out, int out_size, void* d_ws, size_t ws_size,
                              hipStream_t stream) {
  const float* x  = (const float*)d_in[0];
  const float* W1 = (const float*)d_in[1];
  const float* b1 = (const float*)d_in[2];
  const float* W2 = (const float*)d_in[3];
  const float* b2 = (const float*)d_in[4];
  float* out = (float*)d_out;

  const int T = 30, B = 4096;

  char* ws = (char*)d_ws;
  _Float16* wB = (_Float16*)ws;                  // 49*8*512 fp16 = 392KB
  size_t off = (size_t)49 * 8 * 512 * sizeof(_Float16);
  off = (off + 255) & ~(size_t)255;
  float* state1 = (float*)(ws + off); off += (size_t)B * 128 * 4;
  float* state2 = (float*)(ws + off); off += (size_t)B * 10 * 4;
  off = (off + 255) & ~(size_t)255;
  float* cur1 = (float*)(ws + off);

  size_t per_t = (size_t)B * 128 * 4;
  size_t avail = (ws_size > off) ? (ws_size - off) : 0;
  int CH = (int)(avail / per_t);
  if (CH > T) CH = T;
  if (CH < 1) CH = 1;

  split_w1<<<(W1N + 255) / 256, 256, 0, stream>>>(W1, wB);

  for (int t0 = 0; t0 < T; t0 += CH) {
    int tn = (t0 + CH < T) ? (t0 + CH) : T;
    int mrows = (tn - t0) * B;                   // multiple of 4096 -> multiple of 128
    gemm1<<<mrows / 128, 256, 0, stream>>>(x, wB, cur1, (long)t0 * B);
    lif<<<B / 4, 256, 0, stream>>>(cur1, b1, W2, b2, out, state1, state2, t0, tn);
  }
}

// Round 7
// 145.575 us; speedup vs baseline: 1.3113x; 1.3113x over previous
//
#include <hip/hip_runtime.h>
#include <stdint.h>

#define THR  1.0f
#define BETA 0.95f
#define SX   4096.0f            // x scale (2^12) -> no fp16 denormal flush
#define SW   512.0f             // W scale (2^9)
#define SINV (1.0f / (4096.0f * 512.0f))
#define W1N  (128 * 784)

typedef __attribute__((ext_vector_type(8)))  _Float16 f16x8;
typedef __attribute__((ext_vector_type(16))) float    f32x16;
typedef __attribute__((ext_vector_type(4)))  float    fvec4;

__device__ __forceinline__ void gll16(const float* g, float* l){
  __builtin_amdgcn_global_load_lds((const __attribute__((address_space(1))) void*)g,
                                   (__attribute__((address_space(3))) void*)l, 16, 0, 0);
}

// 2-term RNE fp16 split of scaled W1, written in MFMA-fragment order:
// fragment (gks 0..48, nf 0..3, term 0..1) is 1KB: lane (kg*32+r) holds 8 fp16
// for col h=nf*32+r, k=gks*16+kg*8.. — a wave's B-load is 1KB fully contiguous.
__global__ void split_w1(const float* __restrict__ W1, _Float16* __restrict__ wB){
  int i = blockIdx.x * 256 + threadIdx.x;
  if (i < W1N) {
    int h = i / 784, k = i % 784;
    float v = W1[i] * SW;
    _Float16 hi = (_Float16)v;
    _Float16 lo = (_Float16)(v - (float)hi);
    int ks = k >> 4, kg = (k >> 3) & 1, j = k & 7, nf = h >> 5, r = h & 31;
    int base = ((ks * 4 + nf) * 2) * 512 + (kg * 32 + r) * 8 + j;
    wB[base]       = hi;   // term 0
    wB[base + 512] = lo;   // term 1
  }
}

// cur1[m][h] = sum_k x[m][k]*W1[h][k] + b1[h] (scaled acc; bias in epilogue).
// Block: 4 waves, tile 128m x 128n. BOTH operands staged via global_load_lds:
//   A: swizzled 128row x 32k f32 slabs (16KB, dbuf)   [0,8192)
//   B: fragment-ordered fp16 slabs (16KB, dbuf)        [8192,16384)
//   A tail 8KB [16384,18432), B tail 8KB [18432,20480). LDS 80KB -> 2 blk/CU.
// B is read by all 4 waves from LDS (4x cut in per-CU L1 traffic vs global).
// 3 fp16 MFMAs (hh+hl+lh) per nf per k-step.
__launch_bounds__(256, 2)
__global__ void gemm1(const float* __restrict__ x,
                      const float* __restrict__ wBf,   // wB viewed as float*
                      const float* __restrict__ b1,
                      float* __restrict__ cur1,
                      long row0){
  __shared__ float lds[20480];
  const int lane = threadIdx.x & 63;
  const int w    = threadIdx.x >> 6;
  const long blk_row0 = row0 + (long)blockIdx.x * 128;
  const int r  = lane & 31;
  const int kg = lane >> 5;
  const int row_a = w * 32 + r;           // this lane's A row within tile
  const int xr  = (row_a & 7) << 4;       // main-slab XOR swizzle (bytes)
  const int xr3 = (row_a & 3) << 4;       // tail XOR swizzle

  // ---- stage tails once: A (k=768..783) 8KB, B (gks=48) 8KB ----
  #pragma unroll
  for (int i = 0; i < 2; ++i) {
    int j = w * 2 + i;                    // 0..7
    int jj = j * 64 + lane;               // 0..511
    int rw = jj >> 2, q = (jj & 3) << 4;
    int kb = q ^ ((rw & 3) << 4);
    gll16(x + (blk_row0 + rw) * 784 + 768 + (kb >> 2), &lds[16384 + j * 256]);
    gll16(wBf + 98304 + j * 256 + lane * 4,            &lds[18432 + j * 256]);
  }

  // stage one 16KB A slab (s = 32-k slab index 0..23)
  #define STAGE_A(bb, s) {                                                   \
    _Pragma("unroll") for (int i = 0; i < 4; ++i) {                          \
      int j = w * 4 + i;                                                     \
      int jj = j * 64 + lane;             /* 0..1023 */                      \
      int rw = jj >> 3, q = (jj & 7) << 4;                                   \
      int kb = q ^ ((rw & 7) << 4);                                          \
      gll16(x + (blk_row0 + rw) * 784 + (s) * 32 + (kb >> 2),                \
            &lds[(bb) * 4096 + j * 256]); } }

  // stage one 16KB B slab (phase p: wB bytes [p*16K, +16K), linear)
  #define STAGE_B(bb, p) {                                                   \
    _Pragma("unroll") for (int i = 0; i < 4; ++i) {                          \
      int j = w * 4 + i;                                                     \
      gll16(wBf + (p) * 4096 + j * 256 + lane * 4,                           \
            &lds[8192 + (bb) * 4096 + j * 256]); } }

  f32x16 acc[4] = {};

  STAGE_A(0, 0);
  STAGE_B(0, 0);
  __syncthreads();                        // drain: slab 0 + tails ready

  #pragma unroll 2
  for (int s = 0; s < 24; ++s) {
    const int bb = s & 1;
    if (s + 1 < 24) { STAGE_A(bb ^ 1, s + 1); STAGE_B(bb ^ 1, s + 1); }
    #pragma unroll
    for (int ksl = 0; ksl < 2; ++ksl) {
      // B fragments from LDS: 8 conflict-free ds_read_b128
      f16x8 b[8];
      #pragma unroll
      for (int f = 0; f < 8; ++f)
        b[f] = *(const f16x8*)&lds[8192 + bb * 4096 + (ksl * 8 + f) * 256 + lane * 4];
      // A fragment: 2 swizzled ds_read_b128 + fp16 split
      int kb0 = ksl * 64 + kg * 32;
      fvec4 a0 = *(const fvec4*)&lds[bb * 4096 + row_a * 32 + (((kb0)      ^ xr) >> 2)];
      fvec4 a1 = *(const fvec4*)&lds[bb * 4096 + row_a * 32 + (((kb0 + 16) ^ xr) >> 2)];
      f16x8 ah, al;
      #pragma unroll
      for (int j = 0; j < 8; ++j) {
        float v = ((j < 4) ? a0[j] : a1[j - 4]) * SX;
        _Float16 hh = (_Float16)v;
        ah[j] = hh; al[j] = (_Float16)(v - (float)hh);
      }
      #pragma unroll
      for (int nf = 0; nf < 4; ++nf) {
        acc[nf] = __builtin_amdgcn_mfma_f32_32x32x16_f16(ah, b[nf * 2],     acc[nf], 0, 0, 0);
        acc[nf] = __builtin_amdgcn_mfma_f32_32x32x16_f16(ah, b[nf * 2 + 1], acc[nf], 0, 0, 0);
        acc[nf] = __builtin_amdgcn_mfma_f32_32x32x16_f16(al, b[nf * 2],     acc[nf], 0, 0, 0);
      }
    }
    __syncthreads();                      // next slab staged, old buf free
  }

  // ---- tail k-step (gks=48) from tail LDS regions ----
  {
    f16x8 b[8];
    #pragma unroll
    for (int f = 0; f < 8; ++f)
      b[f] = *(const f16x8*)&lds[18432 + f * 256 + lane * 4];
    int kb0 = kg * 32;
    fvec4 a0 = *(const fvec4*)&lds[16384 + row_a * 16 + (((kb0)      ^ xr3) >> 2)];
    fvec4 a1 = *(const fvec4*)&lds[16384 + row_a * 16 + (((kb0 + 16) ^ xr3) >> 2)];
    f16x8 ah, al;
    #pragma unroll
    for (int j = 0; j < 8; ++j) {
      float v = ((j < 4) ? a0[j] : a1[j - 4]) * SX;
      _Float16 hh = (_Float16)v;
      ah[j] = hh; al[j] = (_Float16)(v - (float)hh);
    }
    #pragma unroll
    for (int nf = 0; nf < 4; ++nf) {
      acc[nf] = __builtin_amdgcn_mfma_f32_32x32x16_f16(ah, b[nf * 2],     acc[nf], 0, 0, 0);
      acc[nf] = __builtin_amdgcn_mfma_f32_32x32x16_f16(ah, b[nf * 2 + 1], acc[nf], 0, 0, 0);
      acc[nf] = __builtin_amdgcn_mfma_f32_32x32x16_f16(al, b[nf * 2],     acc[nf], 0, 0, 0);
    }
  }

  // C/D layout (m74/m101-verified): col = lane&31, row = (reg&3)+8*(reg>>2)+4*(lane>>5)
  float b1v[4];
  #pragma unroll
  for (int nf = 0; nf < 4; ++nf) b1v[nf] = b1[nf * 32 + r];
  long m0 = (long)blockIdx.x * 128 + w * 32;
  #pragma unroll
  for (int nf = 0; nf < 4; ++nf)
    #pragma unroll
    for (int reg = 0; reg < 16; ++reg) {
      int rr = (reg & 3) + 8 * (reg >> 2) + 4 * kg;
      cur1[(m0 + rr) * 128 + nf * 32 + r] = acc[nf][reg] * SINV + b1v[nf];
    }
  #undef STAGE_A
  #undef STAGE_B
}

// LIF recurrence + layer 2 (bias1 already folded into cur1).
__launch_bounds__(256)
__global__ void lif(const float* __restrict__ cur1,
                    const float* __restrict__ W2,
                    const float* __restrict__ b2,
                    float* __restrict__ out,
                    float* __restrict__ state1,
                    float* __restrict__ state2,
                    int t0, int tn){
  const int lane = threadIdx.x & 63;
  const int b = blockIdx.x * 4 + (threadIdx.x >> 6);
  const int o = lane & 15;
  const int c = lane >> 4;

  float wv[32];
  #pragma unroll
  for (int j = 0; j < 32; ++j) wv[j] = 0.f;
  if (o < 10) {
    #pragma unroll
    for (int j = 0; j < 32; ++j) wv[j] = W2[o * 128 + c * 32 + j];
  }
  float b2v = (lane < 10) ? b2[lane] : 0.f;

  float mem1a, mem1b, mem2;
  if (t0 == 0) { mem1a = 0.f; mem1b = 0.f; mem2 = 0.f; }
  else {
    mem1a = state1[b * 128 + lane];
    mem1b = state1[b * 128 + 64 + lane];
    mem2  = (lane < 10) ? state2[b * 10 + lane] : 0.f;
  }

  for (int t = t0; t < tn; ++t) {
    long base = ((long)(t - t0) * 4096 + b) * 128;
    float c1a = cur1[base + lane];
    float c1b = cur1[base + 64 + lane];
    float r1a = (mem1a > THR) ? THR : 0.f;
    float r1b = (mem1b > THR) ? THR : 0.f;
    mem1a = BETA * mem1a + c1a - r1a;
    mem1b = BETA * mem1b + c1b - r1b;

    uint64_t mA = __ballot(mem1a > THR);
    uint64_t mB = __ballot(mem1b > THR);
    uint64_t m64 = (c & 2) ? mB : mA;
    uint32_t bits = (uint32_t)(m64 >> ((c & 1) << 5));

    float s = 0.f;
    #pragma unroll
    for (int j = 0; j < 32; ++j)
      s = fmaf((float)((bits >> j) & 1u), wv[j], s);   // bfe+cvt+fma
    s += __shfl_xor(s, 16);
    s += __shfl_xor(s, 32);

    if (lane < 10) {
      float cur2 = s + b2v;
      float r2 = (mem2 > THR) ? THR : 0.f;
      mem2 = BETA * mem2 + cur2 - r2;
      float s2 = (mem2 > THR) ? 1.f : 0.f;
      long ob = (long)t * 40960 + (long)b * 10 + lane;
      out[ob] = s2;
      out[1228800 + ob] = mem2;
    }
  }

  if (tn < 30) {
    state1[b * 128 + lane] = mem1a;
    state1[b * 128 + 64 + lane] = mem1b;
    if (lane < 10) state2[b * 10 + lane] = mem2;
  }
}

extern "C" void kernel_launch(void* const* d_in, const int* in_sizes, int n_in,
                              void* d_out, int out_size, void* d_ws, size_t ws_size,
                              hipStream_t stream) {
  const float* x  = (const float*)d_in[0];
  const float* W1 = (const float*)d_in[1];
  const float* b1 = (const float*)d_in[2];
  const float* W2 = (const float*)d_in[3];
  const float* b2 = (const float*)d_in[4];
  float* out = (float*)d_out;

  const int T = 30, B = 4096;

  char* ws = (char*)d_ws;
  _Float16* wB = (_Float16*)ws;                  // 49*8*512 fp16 = 392KB
  size_t off = (size_t)49 * 8 * 512 * sizeof(_Float16);
  off = (off + 255) & ~(size_t)255;
  float* state1 = (float*)(ws + off); off += (size_t)B * 128 * 4;
  float* state2 = (float*)(ws + off); off += (size_t)B * 10 * 4;
  off = (off + 255) & ~(size_t)255;
  float* cur1 = (float*)(ws + off);

  size_t per_t = (size_t)B * 128 * 4;
  size_t avail = (ws_size > off) ? (ws_size - off) : 0;
  int CH = (int)(avail / per_t);
  if (CH > T) CH = T;
  if (CH < 1) CH = 1;

  split_w1<<<(W1N + 255) / 256, 256, 0, stream>>>(W1, wB);

  for (int t0 = 0; t0 < T; t0 += CH) {
    int tn = (t0 + CH < T) ? (t0 + CH) : T;
    int mrows = (tn - t0) * B;                   // multiple of 4096 -> multiple of 128
    gemm1<<<mrows / 128, 256, 0, stream>>>(x, (const float*)wB, b1, cur1, (long)t0 * B);
    lif<<<B / 4, 256, 0, stream>>>(cur1, W2, b2, out, state1, state2, t0, tn);
  }
}

// Round 9
// 144.749 us; speedup vs baseline: 1.3187x; 1.0057x over previous
//
#include <hip/hip_runtime.h>
#include <stdint.h>

#define THR  1.0f
#define BETA 0.95f
#define SX   4096.0f            // x scale (2^12) -> no fp16 denormal flush
#define SW   512.0f             // W scale (2^9)
#define SINV (1.0f / (4096.0f * 512.0f))
#define W1N  (128 * 784)

typedef __attribute__((ext_vector_type(8)))  _Float16 f16x8;
typedef __attribute__((ext_vector_type(16))) float    f32x16;
typedef __attribute__((ext_vector_type(4)))  float    fvec4;

__device__ __forceinline__ void gll16(const float* g, float* l){
  __builtin_amdgcn_global_load_lds((const __attribute__((address_space(1))) void*)g,
                                   (__attribute__((address_space(3))) void*)l, 16, 0, 0);
}

// 2-term RNE fp16 split of scaled W1, written in MFMA-fragment order:
// fragment (gks 0..48, nf 0..3, term 0..1) is 1KB: lane (kg*32+r) holds 8 fp16
// for col h=nf*32+r, k=gks*16+kg*8.. — a wave's B-load is 1KB fully contiguous.
__global__ void split_w1(const float* __restrict__ W1, _Float16* __restrict__ wB){
  int i = blockIdx.x * 256 + threadIdx.x;
  if (i < W1N) {
    int h = i / 784, k = i % 784;
    float v = W1[i] * SW;
    _Float16 hi = (_Float16)v;
    _Float16 lo = (_Float16)(v - (float)hi);
    int ks = k >> 4, kg = (k >> 3) & 1, j = k & 7, nf = h >> 5, r = h & 31;
    int base = ((ks * 4 + nf) * 2) * 512 + (kg * 32 + r) * 8 + j;
    wB[base]       = hi;   // term 0
    wB[base + 512] = lo;   // term 1
  }
}

// cur1[m][h] = sum_k x[m][k]*W1[h][k] + b1[h] (scaled acc; bias in epilogue).
// Block: 4 waves, tile 128m x 128n. Both operands via global_load_lds, dbuf:
//   A slabs [0,8192) f32, B slabs [8192,16384), A tail [16384,18432),
//   B tail [18432,20480). 80KB LDS -> 2 blocks/CU.
// Counted-vmcnt pipeline (T3/T4): raw s_barrier, vmcnt(8) keeps the next
// slab's 8 loads/wave in flight across the barrier; vmcnt(0) only at slab 23.
__launch_bounds__(256, 2)
__global__ void gemm1(const float* __restrict__ x,
                      const float* __restrict__ wBf,   // wB viewed as float*
                      const float* __restrict__ b1,
                      float* __restrict__ cur1,
                      long row0){
  __shared__ float lds[20480];
  const int lane = threadIdx.x & 63;
  const int w    = threadIdx.x >> 6;
  const long blk_row0 = row0 + (long)blockIdx.x * 128;
  const int r  = lane & 31;
  const int kg = lane >> 5;
  const int row_a = w * 32 + r;           // this lane's A row within tile
  const int xr  = (row_a & 7) << 4;       // main-slab XOR swizzle (bytes)
  const int xr3 = (row_a & 3) << 4;       // tail XOR swizzle

  // stage one 16KB A slab (s = 32-k slab index 0..23) into buffer bb
  #define STAGE_A(bb, s) {                                                   \
    _Pragma("unroll") for (int i = 0; i < 4; ++i) {                          \
      int j = w * 4 + i;                                                     \
      int jj = j * 64 + lane;             /* 0..1023 */                      \
      int rw = jj >> 3, q = (jj & 7) << 4;                                   \
      int kb = q ^ ((rw & 7) << 4);                                          \
      gll16(x + (blk_row0 + rw) * 784 + (s) * 32 + (kb >> 2),                \
            &lds[(bb) * 4096 + j * 256]); } }

  // stage one 16KB B slab (phase p: wB bytes [p*16K, +16K), linear)
  #define STAGE_B(bb, p) {                                                   \
    _Pragma("unroll") for (int i = 0; i < 4; ++i) {                          \
      int j = w * 4 + i;                                                     \
      gll16(wBf + (p) * 4096 + j * 256 + lane * 4,                           \
            &lds[8192 + (bb) * 4096 + j * 256]); } }

  // consume slab in buffer bb: 2 k-steps of 16, 12 MFMA each
  #define COMPUTE(bb) {                                                      \
    _Pragma("unroll") for (int ksl = 0; ksl < 2; ++ksl) {                    \
      f16x8 b[8];                                                            \
      _Pragma("unroll") for (int f = 0; f < 8; ++f)                          \
        b[f] = *(const f16x8*)&lds[8192 + (bb) * 4096 + (ksl * 8 + f) * 256 + lane * 4]; \
      int kb0 = ksl * 64 + kg * 32;                                          \
      fvec4 a0 = *(const fvec4*)&lds[(bb) * 4096 + row_a * 32 + (((kb0)      ^ xr) >> 2)]; \
      fvec4 a1 = *(const fvec4*)&lds[(bb) * 4096 + row_a * 32 + (((kb0 + 16) ^ xr) >> 2)]; \
      f16x8 ah, al;                                                          \
      _Pragma("unroll") for (int j = 0; j < 8; ++j) {                        \
        float v = ((j < 4) ? a0[j] : a1[j - 4]) * SX;                        \
        _Float16 hh = (_Float16)v;                                           \
        ah[j] = hh; al[j] = (_Float16)(v - (float)hh);                       \
      }                                                                      \
      _Pragma("unroll") for (int nf = 0; nf < 4; ++nf) {                     \
        acc[nf] = __builtin_amdgcn_mfma_f32_32x32x16_f16(ah, b[nf * 2],     acc[nf], 0, 0, 0); \
        acc[nf] = __builtin_amdgcn_mfma_f32_32x32x16_f16(ah, b[nf * 2 + 1], acc[nf], 0, 0, 0); \
        acc[nf] = __builtin_amdgcn_mfma_f32_32x32x16_f16(al, b[nf * 2],     acc[nf], 0, 0, 0); \
      } } }

  // fences
  #define FENCE_A() { __builtin_amdgcn_sched_barrier(0);                     \
    asm volatile("s_waitcnt lgkmcnt(0)" ::: "memory");                       \
    __builtin_amdgcn_s_barrier();                                            \
    asm volatile("" ::: "memory"); }
  #define FENCE_B(vm) {                                                      \
    asm volatile("s_waitcnt vmcnt(" #vm ")" ::: "memory");                   \
    __builtin_amdgcn_s_barrier();                                            \
    asm volatile("" ::: "memory");                                           \
    __builtin_amdgcn_sched_barrier(0); }

  f32x16 acc[4] = {};

  // ---- prologue: tails (4 loads/wave), slab0 (8), slab1 (8) ----
  #pragma unroll
  for (int i = 0; i < 2; ++i) {
    int j = w * 2 + i;                    // 0..7
    int jj = j * 64 + lane;               // 0..511
    int rw = jj >> 2, q = (jj & 3) << 4;
    int kb = q ^ ((rw & 3) << 4);
    gll16(x + (blk_row0 + rw) * 784 + 768 + (kb >> 2), &lds[16384 + j * 256]);
    gll16(wBf + 98304 + j * 256 + lane * 4,            &lds[18432 + j * 256]);
  }
  STAGE_A(0, 0); STAGE_B(0, 0);
  STAGE_A(1, 1); STAGE_B(1, 1);
  FENCE_B(8);                             // tails + slab0 landed; slab1 in flight
  COMPUTE(0);                             // slab 0

  // ---- main loop: slabs 1..22 (stage s+1, keep 8 loads in flight) ----
  for (int q = 0; q < 11; ++q) {
    const int p1 = 2 * q + 1;             // odd slab, buf1; stage p1+1 -> buf0
    FENCE_A();
    STAGE_A(0, p1 + 1); STAGE_B(0, p1 + 1);
    FENCE_B(8);
    COMPUTE(1);
    const int p2 = 2 * q + 2;             // even slab, buf0; stage p2+1 -> buf1
    FENCE_A();
    STAGE_A(1, p2 + 1); STAGE_B(1, p2 + 1);
    FENCE_B(8);
    COMPUTE(0);
  }

  // ---- final slab 23 (buf1), no further stages ----
  FENCE_A();
  FENCE_B(0);
  COMPUTE(1);

  // ---- tail k-step (gks=48) from tail LDS regions ----
  {
    f16x8 b[8];
    #pragma unroll
    for (int f = 0; f < 8; ++f)
      b[f] = *(const f16x8*)&lds[18432 + f * 256 + lane * 4];
    int kb0 = kg * 32;
    fvec4 a0 = *(const fvec4*)&lds[16384 + row_a * 16 + (((kb0)      ^ xr3) >> 2)];
    fvec4 a1 = *(const fvec4*)&lds[16384 + row_a * 16 + (((kb0 + 16) ^ xr3) >> 2)];
    f16x8 ah, al;
    #pragma unroll
    for (int j = 0; j < 8; ++j) {
      float v = ((j < 4) ? a0[j] : a1[j - 4]) * SX;
      _Float16 hh = (_Float16)v;
      ah[j] = hh; al[j] = (_Float16)(v - (float)hh);
    }
    #pragma unroll
    for (int nf = 0; nf < 4; ++nf) {
      acc[nf] = __builtin_amdgcn_mfma_f32_32x32x16_f16(ah, b[nf * 2],     acc[nf], 0, 0, 0);
      acc[nf] = __builtin_amdgcn_mfma_f32_32x32x16_f16(ah, b[nf * 2 + 1], acc[nf], 0, 0, 0);
      acc[nf] = __builtin_amdgcn_mfma_f32_32x32x16_f16(al, b[nf * 2],     acc[nf], 0, 0, 0);
    }
  }

  // C/D layout (m74/m101-verified): col = lane&31, row = (reg&3)+8*(reg>>2)+4*(lane>>5)
  float b1v[4];
  #pragma unroll
  for (int nf = 0; nf < 4; ++nf) b1v[nf] = b1[nf * 32 + r];
  long m0 = (long)blockIdx.x * 128 + w * 32;
  #pragma unroll
  for (int nf = 0; nf < 4; ++nf)
    #pragma unroll
    for (int reg = 0; reg < 16; ++reg) {
      int rr = (reg & 3) + 8 * (reg >> 2) + 4 * kg;
      cur1[(m0 + rr) * 128 + nf * 32 + r] = acc[nf][reg] * SINV + b1v[nf];
    }
  #undef STAGE_A
  #undef STAGE_B
  #undef COMPUTE
  #undef FENCE_A
  #undef FENCE_B
}

// LIF recurrence + layer 2 (bias1 already folded into cur1).
__launch_bounds__(256)
__global__ void lif(const float* __restrict__ cur1,
                    const float* __restrict__ W2,
                    const float* __restrict__ b2,
                    float* __restrict__ out,
                    float* __restrict__ state1,
                    float* __restrict__ state2,
                    int t0, int tn){
  const int lane = threadIdx.x & 63;
  const int b = blockIdx.x * 4 + (threadIdx.x >> 6);
  const int o = lane & 15;
  const int c = lane >> 4;

  float wv[32];
  #pragma unroll
  for (int j = 0; j < 32; ++j) wv[j] = 0.f;
  if (o < 10) {
    #pragma unroll
    for (int j = 0; j < 32; ++j) wv[j] = W2[o * 128 + c * 32 + j];
  }
  float b2v = (lane < 10) ? b2[lane] : 0.f;

  float mem1a, mem1b, mem2;
  if (t0 == 0) { mem1a = 0.f; mem1b = 0.f; mem2 = 0.f; }
  else {
    mem1a = state1[b * 128 + lane];
    mem1b = state1[b * 128 + 64 + lane];
    mem2  = (lane < 10) ? state2[b * 10 + lane] : 0.f;
  }

  for (int t = t0; t < tn; ++t) {
    long base = ((long)(t - t0) * 4096 + b) * 128;
    float c1a = cur1[base + lane];
    float c1b = cur1[base + 64 + lane];
    float r1a = (mem1a > THR) ? THR : 0.f;
    float r1b = (mem1b > THR) ? THR : 0.f;
    mem1a = BETA * mem1a + c1a - r1a;
    mem1b = BETA * mem1b + c1b - r1b;

    uint64_t mA = __ballot(mem1a > THR);
    uint64_t mB = __ballot(mem1b > THR);
    uint64_t m64 = (c & 2) ? mB : mA;
    uint32_t bits = (uint32_t)(m64 >> ((c & 1) << 5));

    float s = 0.f;
    #pragma unroll
    for (int j = 0; j < 32; ++j)
      s = fmaf((float)((bits >> j) & 1u), wv[j], s);   // bfe+cvt+fma
    s += __shfl_xor(s, 16);
    s += __shfl_xor(s, 32);

    if (lane < 10) {
      float cur2 = s + b2v;
      float r2 = (mem2 > THR) ? THR : 0.f;
      mem2 = BETA * mem2 + cur2 - r2;
      float s2 = (mem2 > THR) ? 1.f : 0.f;
      long ob = (long)t * 40960 + (long)b * 10 + lane;
      out[ob] = s2;
      out[1228800 + ob] = mem2;
    }
  }

  if (tn < 30) {
    state1[b * 128 + lane] = mem1a;
    state1[b * 128 + 64 + lane] = mem1b;
    if (lane < 10) state2[b * 10 + lane] = mem2;
  }
}

extern "C" void kernel_launch(void* const* d_in, const int* in_sizes, int n_in,
                              void* d_out, int out_size, void* d_ws, size_t ws_size,
                              hipStream_t stream) {
  const float* x  = (const float*)d_in[0];
  const float* W1 = (const float*)d_in[1];
  const float* b1 = (const float*)d_in[2];
  const float* W2 = (const float*)d_in[3];
  const float* b2 = (const float*)d_in[4];
  float* out = (float*)d_out;

  const int T = 30, B = 4096;

  char* ws = (char*)d_ws;
  _Float16* wB = (_Float16*)ws;                  // 49*8*512 fp16 = 392KB
  size_t off = (size_t)49 * 8 * 512 * sizeof(_Float16);
  off = (off + 255) & ~(size_t)255;
  float* state1 = (float*)(ws + off); off += (size_t)B * 128 * 4;
  float* state2 = (float*)(ws + off); off += (size_t)B * 10 * 4;
  off = (off + 255) & ~(size_t)255;
  float* cur1 = (float*)(ws + off);

  size_t per_t = (size_t)B * 128 * 4;
  size_t avail = (ws_size > off) ? (ws_size - off) : 0;
  int CH = (int)(avail / per_t);
  if (CH > T) CH = T;
  if (CH < 1) CH = 1;

  split_w1<<<(W1N + 255) / 256, 256, 0, stream>>>(W1, wB);

  for (int t0 = 0; t0 < T; t0 += CH) {
    int tn = (t0 + CH < T) ? (t0 + CH) : T;
    int mrows = (tn - t0) * B;                   // multiple of 4096 -> multiple of 128
    gemm1<<<mrows / 128, 256, 0, stream>>>(x, (const float*)wB, b1, cur1, (long)t0 * B);
    lif<<<B / 4, 256, 0, stream>>>(cur1, W2, b2, out, state1, state2, t0, tn);
  }
}